// Round 1
// baseline (783.951 us; speedup 1.0000x reference)
//
#include <hip/hip_runtime.h>
#include <hip/hip_bf16.h>
#include <math.h>

// Problem constants
#define B_ROWS 8192
#define D_IN 1024
#define D_OUT 1024
#define NEXP 16
#define KDIM 8
// GEMM cols: 15*8 z-cols (0..119), 16*8 a-cols (120..247), pad to 256
#define NCOL 256

// ---------------- K0: pack/transpose weights into Wt[d][col] ----------------
__global__ void wt_pack_kernel(const float* __restrict__ Wz,
                               const float* __restrict__ Ww,
                               float* __restrict__ Wt) {
    int d = blockIdx.x;        // 0..1023
    int col = threadIdx.x;     // 0..255
    float v = 0.0f;
    if (col < 120) {
        int n = col >> 3, k = col & 7;
        v = Wz[n * (D_IN * 8) + d * 8 + k];
    } else if (col < 248) {
        int c = col - 120;
        int n = c >> 3, k = c & 7;
        v = Ww[n * (D_IN * 8) + d * 8 + k];
    }
    Wt[d * NCOL + col] = v;
}

// ---------------- K1: ZA[8192][256] = x[8192][1024] @ Wt[1024][256] ---------
// BM=64, BN=64, KC=16, 256 threads, 4x4 register tile.
#define BM 64
#define BN 64
#define KC 16
__global__ __launch_bounds__(256) void gemm_kernel(const float* __restrict__ x,
                                                   const float* __restrict__ Wt,
                                                   float* __restrict__ ZA) {
    __shared__ float xs[KC][BM];
    __shared__ float wsh[KC][BN];

    const int tid = threadIdx.x;
    const int bRow = blockIdx.x;   // 0..127
    const int bCol = blockIdx.y;   // 0..3
    const int tr = tid >> 4;       // 0..15 (row group of 4)
    const int tc = tid & 15;       // 0..15 (col group of 4)

    // global x load mapping: 64 rows x 16 k per chunk, 1 float4/thread
    const int lxRow = tid >> 2;          // 0..63
    const int lxK = (tid & 3) << 2;      // 0,4,8,12
    // global W load mapping: 16 k x 64 cols per chunk, 1 float4/thread
    const int lwK = tid >> 4;            // 0..15
    const int lwC = (tid & 15) << 2;     // 0..60

    const float* xg = x + (bRow * BM + lxRow) * D_IN + lxK;
    const float* wg = Wt + lwK * NCOL + bCol * BN + lwC;

    float4 px = *(const float4*)xg;
    float4 pw = *(const float4*)wg;

    float acc[4][4];
#pragma unroll
    for (int i = 0; i < 4; ++i)
#pragma unroll
        for (int j = 0; j < 4; ++j) acc[i][j] = 0.0f;

    for (int kc = 0; kc < D_IN; kc += KC) {
        // commit prefetched chunk to LDS
        xs[lxK + 0][lxRow] = px.x;
        xs[lxK + 1][lxRow] = px.y;
        xs[lxK + 2][lxRow] = px.z;
        xs[lxK + 3][lxRow] = px.w;
        *(float4*)&wsh[lwK][lwC] = pw;
        __syncthreads();
        // prefetch next chunk (hides global latency under compute)
        if (kc + KC < D_IN) {
            px = *(const float4*)(xg + kc + KC);
            pw = *(const float4*)(wg + (kc + KC) * NCOL);
        }
#pragma unroll
        for (int kk = 0; kk < KC; ++kk) {
            const float4 xa = *(const float4*)&xs[kk][tr << 2];
            const float4 wv = *(const float4*)&wsh[kk][tc << 2];
            const float xr[4] = {xa.x, xa.y, xa.z, xa.w};
            const float wc[4] = {wv.x, wv.y, wv.z, wv.w};
#pragma unroll
            for (int i = 0; i < 4; ++i)
#pragma unroll
                for (int j = 0; j < 4; ++j) acc[i][j] += xr[i] * wc[j];
        }
        __syncthreads();
    }

    const int row0 = bRow * BM + (tr << 2);
    const int col0 = bCol * BN + (tc << 2);
#pragma unroll
    for (int i = 0; i < 4; ++i) {
        float4 o;
        o.x = acc[i][0]; o.y = acc[i][1]; o.z = acc[i][2]; o.w = acc[i][3];
        *(float4*)&ZA[(row0 + i) * NCOL + col0] = o;
    }
}

// ---------------- K2: per-row tree probs + softmax + permutation mix --------
// 128 threads per block, one block per row. Thread = entry e = kk*16 + n.
__global__ __launch_bounds__(128) void gate_kernel(const float* __restrict__ ZA,
                                                   const float* __restrict__ bz,
                                                   const float* __restrict__ bw,
                                                   const float* __restrict__ perm,
                                                   float* __restrict__ wout) {
    __shared__ float red[128];
    __shared__ float u[128];

    const int b = blockIdx.x;
    const int tid = threadIdx.x;
    const int kk = tid >> 4;   // 0..7
    const int n = tid & 15;    // 0..15

    const float* za = ZA + b * NCOL;

    // tree probability for leaf n at tree-index kk
    float prob = 1.0f;
#pragma unroll
    for (int L = 0; L < 4; ++L) {
        const int node = (1 << L) - 1 + (n >> (4 - L));
        const int bit = (n >> (3 - L)) & 1;
        const float v = za[node * 8 + kk] + bz[node * 8 + kk];
        float p;
        if (v <= -0.5f) p = 0.0f;
        else if (v >= 0.5f) p = 1.0f;
        else p = fmaf(-2.0f * v * v, v, fmaf(1.5f, v, 0.5f));
        prob *= bit ? (1.0f - p) : p;
    }

    const float a = za[120 + n * 8 + kk] + bw[n * 8 + kk];
    const float logit = (prob <= 0.0f) ? -3.4e38f : (a + logf(prob + 1e-8f));

    // max-reduce over 128 entries
    red[tid] = logit;
    __syncthreads();
#pragma unroll
    for (int s = 64; s > 0; s >>= 1) {
        if (tid < s) red[tid] = fmaxf(red[tid], red[tid + s]);
        __syncthreads();
    }
    const float mx = red[0];
    __syncthreads();

    // unnormalized softmax (denominator cancels in final normalization)
    u[tid] = expf(logit - mx);
    __syncthreads();

    // w~[l] = sum_e u[e] * perm[kk(e)][n(e)][l]; thread (chunk,l) does 16 MACs
    const int l = tid & 15;
    const int chunk = tid >> 4;  // 0..7
    float partial = 0.0f;
#pragma unroll
    for (int e0 = 0; e0 < 16; ++e0) {
        const int e = chunk * 16 + e0;
        partial += u[e] * perm[(e >> 4) * 256 + (e & 15) * 16 + l];
    }
    red[tid] = partial;
    __syncthreads();
#pragma unroll
    for (int s = 64; s >= 16; s >>= 1) {
        if (tid < s) red[tid] += red[tid + s];
        __syncthreads();
    }
    // red[0..15] = w~[l]
    if (tid < 16) {
        float tot = 0.0f;
#pragma unroll
        for (int l2 = 0; l2 < 16; ++l2) tot += red[l2];
        wout[b * NEXP + tid] = red[tid] / tot;
    }
}

// ---------------- K3: y[b,d] = sum_n f[b,d,n] * w[b,n] ----------------------
__global__ __launch_bounds__(256) void out_kernel(const float* __restrict__ f,
                                                  const float* __restrict__ w,
                                                  float* __restrict__ y) {
    __shared__ float ws_[16];
    const int b = blockIdx.x >> 2;                       // 0..8191
    const int d = ((blockIdx.x & 3) << 8) + threadIdx.x; // 0..1023
    if (threadIdx.x < 16) ws_[threadIdx.x] = w[b * NEXP + threadIdx.x];
    __syncthreads();

    const long idx = (long)b * D_OUT + d;
    const float4* f4 = (const float4*)(f + idx * NEXP);
    const float4 a0 = f4[0];
    const float4 a1 = f4[1];
    const float4 a2 = f4[2];
    const float4 a3 = f4[3];

    float r = a0.x * ws_[0] + a0.y * ws_[1] + a0.z * ws_[2] + a0.w * ws_[3]
            + a1.x * ws_[4] + a1.y * ws_[5] + a1.z * ws_[6] + a1.w * ws_[7]
            + a2.x * ws_[8] + a2.y * ws_[9] + a2.z * ws_[10] + a2.w * ws_[11]
            + a3.x * ws_[12] + a3.y * ws_[13] + a3.z * ws_[14] + a3.w * ws_[15];
    y[idx] = r;
}

// ---------------- launch ----------------------------------------------------
extern "C" void kernel_launch(void* const* d_in, const int* in_sizes, int n_in,
                              void* d_out, int out_size, void* d_ws, size_t ws_size,
                              hipStream_t stream) {
    const float* f = (const float*)d_in[0];     // (8192, 1024, 16)
    const float* x = (const float*)d_in[1];     // (8192, 1024)
    const float* perm = (const float*)d_in[2];  // (8, 16, 16)
    const float* Wz = (const float*)d_in[3];    // (15, 1024, 8)
    const float* bz = (const float*)d_in[4];    // (15, 8)
    const float* Ww = (const float*)d_in[5];    // (16, 1024, 8)
    const float* bw = (const float*)d_in[6];    // (16, 8)
    float* y = (float*)d_out;                   // (8192, 1024)

    // workspace layout
    float* Wt = (float*)d_ws;                    // 1024*256 = 262144 floats
    float* ZA = Wt + D_IN * NCOL;                // 8192*256 = 2097152 floats
    float* Wexp = ZA + B_ROWS * NCOL;            // 8192*16  = 131072 floats

    // K0: pack weights
    wt_pack_kernel<<<dim3(D_IN), dim3(NCOL), 0, stream>>>(Wz, Ww, Wt);
    // K1: gating GEMM
    gemm_kernel<<<dim3(B_ROWS / BM, NCOL / BN), dim3(256), 0, stream>>>(x, Wt, ZA);
    // K2: tree + softmax + permutation mix
    gate_kernel<<<dim3(B_ROWS), dim3(128), 0, stream>>>(ZA, bz, bw, perm, Wexp);
    // K3: weighted expert sum
    out_kernel<<<dim3(B_ROWS * 4), dim3(256), 0, stream>>>(f, Wexp, y);
}